// Round 6
// baseline (326.439 us; speedup 1.0000x reference)
//
#include <hip/hip_runtime.h>
#include <float.h>
#include <math.h>

#define TOKENS 16384
#define HIDDEN 2048
#define NEXP 128
#define TOPK 8
#define NCAND 12      // refine candidate depth
#define DELTA 1e-3f

#define BM 64
#define BK 64
#define KITERS (HIDDEN / BK)   // 32

typedef float f32x16 __attribute__((ext_vector_type(16)));
typedef short bf16x8 __attribute__((ext_vector_type(8)));

__device__ __forceinline__ unsigned pack_hi(float a, float b) {
    return (__float_as_uint(a) >> 16) | (__float_as_uint(b) & 0xFFFF0000u);
}
__device__ __forceinline__ float resid(float a) {
    return a - __uint_as_float(__float_as_uint(a) & 0xFFFF0000u);
}

__device__ __forceinline__ void load_lds_16B(const void* g, void* l) {
    __builtin_amdgcn_global_load_lds(
        (const __attribute__((address_space(1))) unsigned int*)g,
        (__attribute__((address_space(3))) unsigned int*)l, 16, 0, 0);
}

// ---------------------------------------------------------------------------
// K0: pre-split W into 32x32x16-fragment-ordered bf16 hi/lo.
// Chunk C = k16*8 + nt*2 + hl; 64 lanes x 16 B each.
// Lane l of chunk: expert = nt*32 + (l&31), k = k16*16 + (l>>5)*8 + j.
// ---------------------------------------------------------------------------
__global__ __launch_bounds__(256) void presplit_w(const float* __restrict__ W,
                                                  unsigned short* __restrict__ Ws) {
    const int c = blockIdx.x * 256 + threadIdx.x;   // [0, 65536)
    const int lane = c & 63;
    const int q = c >> 6;
    const int hl = q & 1;
    const int nt = (q >> 1) & 3;
    const int k16 = q >> 3;
    const int e = nt * 32 + (lane & 31);
    const int k0 = k16 * 16 + (lane >> 5) * 8;
    const float* wp = W + (size_t)e * HIDDEN + k0;
    float4 a = *(const float4*)wp;
    float4 b = *(const float4*)(wp + 4);
    if (hl) {
        a.x = resid(a.x); a.y = resid(a.y); a.z = resid(a.z); a.w = resid(a.w);
        b.x = resid(b.x); b.y = resid(b.y); b.z = resid(b.z); b.w = resid(b.w);
    }
    uint4 o;
    o.x = pack_hi(a.x, a.y); o.y = pack_hi(a.z, a.w);
    o.z = pack_hi(b.x, b.y); o.w = pack_hi(b.z, b.w);
    *(uint4*)(Ws + (size_t)c * 8) = o;
}

// ---------------------------------------------------------------------------
// K1: split-bf16 GEMM on 32x32x16 MFMA. BM=64 x BN=128 x BK=64, grid 256
// (1 block/CU), 256 thr = 4 waves: wm=wid&1 (32-token group), wn=wid>>1
// (64-expert group). Wave tile 32 tok x 64 exp = 2 acc tiles (32 VGPRs).
// Single-buffered LDS, 2 barriers/iter: B-DMA issued AND drained within the
// same iter (no cross-iter vmcnt(0) poison); X prefetched 1 iter in regs.
// A frag (s,hl): lane l -> token wm*32+(l&31), k = s*16+(l>>5)*8+j.
// C/D (m74-verified): col=lane&31, row=(reg&3)+8*(reg>>2)+4*(lane>>5).
// ---------------------------------------------------------------------------
__global__ __launch_bounds__(256) void router_gemm(const float* __restrict__ X,
                                                   const unsigned short* __restrict__ Ws,
                                                   float* __restrict__ logits) {
    __shared__ unsigned short sA[16 * 512];   // 16 KB: chunk (wm*4+s)*2+hl
    __shared__ unsigned short sB[32 * 512];   // 32 KB: chunk (s*4+nt)*2+hl
    const int tid = threadIdx.x;
    const int lane = tid & 63;
    const int wid = tid >> 6;
    const int wm = wid & 1, wn = wid >> 1;
    const int t0 = blockIdx.x * BM;

    // A staging map: thread -> (swm = tid>>7, ss = (tid>>5)&3, stok = tid&31);
    // loads 16 consecutive floats (64 B, one full line) of one token row.
    const int swm = tid >> 7, ss = (tid >> 5) & 3, stok = tid & 31;
    const float* Xp = X + (size_t)(t0 + swm * 32 + stok) * HIDDEN + ss * 16;
    const int cA0 = ((swm * 4 + ss) * 2) * 512;   // hl=0 chunk base (ushorts)

    f32x16 acc[2];
#pragma unroll
    for (int i = 0; i < 2; ++i)
#pragma unroll
        for (int r = 0; r < 16; ++r) acc[i][r] = 0.f;

    // prefetch iter 0
    float4 xv0 = *(const float4*)(Xp);
    float4 xv1 = *(const float4*)(Xp + 4);
    float4 xv2 = *(const float4*)(Xp + 8);
    float4 xv3 = *(const float4*)(Xp + 12);

#pragma unroll 1
    for (int kt = 0; kt < KITERS; ++kt) {
        __syncthreads();   // everyone done reading LDS of prev iter
        // ---- B DMA: this wave stages chunks wid*8 .. wid*8+7 of this iter's
        // 32 KB slab (Ws is slab-contiguous: global chunk = kt*32 + c).
        {
            const unsigned short* src = Ws + ((size_t)kt * 32 + wid * 8) * 512 + lane * 8;
            unsigned short* dst = &sB[(wid * 8) * 512];
#pragma unroll
            for (int i = 0; i < 8; ++i)
                load_lds_16B(src + i * 512, dst + i * 512);
        }
        // ---- A stage: convert prefetched 16 floats -> hi/lo frag halves
        {
            uint4 v;
            v.x = pack_hi(xv0.x, xv0.y); v.y = pack_hi(xv0.z, xv0.w);
            v.z = pack_hi(xv1.x, xv1.y); v.w = pack_hi(xv1.z, xv1.w);
            *(uint4*)&sA[cA0 + stok * 8] = v;                    // hl0, half0
            v.x = pack_hi(xv2.x, xv2.y); v.y = pack_hi(xv2.z, xv2.w);
            v.z = pack_hi(xv3.x, xv3.y); v.w = pack_hi(xv3.z, xv3.w);
            *(uint4*)&sA[cA0 + (32 + stok) * 8] = v;             // hl0, half1
            v.x = pack_hi(resid(xv0.x), resid(xv0.y)); v.y = pack_hi(resid(xv0.z), resid(xv0.w));
            v.z = pack_hi(resid(xv1.x), resid(xv1.y)); v.w = pack_hi(resid(xv1.z), resid(xv1.w));
            *(uint4*)&sA[cA0 + 512 + stok * 8] = v;              // hl1, half0
            v.x = pack_hi(resid(xv2.x), resid(xv2.y)); v.y = pack_hi(resid(xv2.z), resid(xv2.w));
            v.z = pack_hi(resid(xv3.x), resid(xv3.y)); v.w = pack_hi(resid(xv3.z), resid(xv3.w));
            *(uint4*)&sA[cA0 + 512 + (32 + stok) * 8] = v;       // hl1, half1
        }
        __syncthreads();   // drains DMA (issued ~100 cyc ago) + A writes

        if (kt + 1 < KITERS) {   // X prefetch for next iter; lands during MFMA
            const float* xp = Xp + (kt + 1) * BK;
            xv0 = *(const float4*)(xp);
            xv1 = *(const float4*)(xp + 4);
            xv2 = *(const float4*)(xp + 8);
            xv3 = *(const float4*)(xp + 12);
        }

        // ---- compute: 4 k16-steps x 2 nt x 3 split-terms = 24 MFMA
#pragma unroll
        for (int s = 0; s < 4; ++s) {
            const int ab = ((wm * 4 + s) * 2) * 512 + lane * 8;
            const bf16x8 ah = *(const bf16x8*)&sA[ab];
            const bf16x8 al = *(const bf16x8*)&sA[ab + 512];
#pragma unroll
            for (int ntl = 0; ntl < 2; ++ntl) {
                const int nt = wn * 2 + ntl;
                const int bb = ((s * 4 + nt) * 2) * 512 + lane * 8;
                const bf16x8 bh = *(const bf16x8*)&sB[bb];
                const bf16x8 bl = *(const bf16x8*)&sB[bb + 512];
                acc[ntl] = __builtin_amdgcn_mfma_f32_32x32x16_bf16(ah, bh, acc[ntl], 0, 0, 0);
                acc[ntl] = __builtin_amdgcn_mfma_f32_32x32x16_bf16(ah, bl, acc[ntl], 0, 0, 0);
                acc[ntl] = __builtin_amdgcn_mfma_f32_32x32x16_bf16(al, bh, acc[ntl], 0, 0, 0);
            }
        }
    }

    // epilogue: col=lane&31, row=(reg&3)+8*(reg>>2)+4*(lane>>5)
    const int col = lane & 31;
    const int rbase = 4 * (lane >> 5);
#pragma unroll
    for (int ntl = 0; ntl < 2; ++ntl) {
        const int e = wn * 64 + ntl * 32 + col;
#pragma unroll
        for (int reg = 0; reg < 16; ++reg) {
            const int row = (reg & 3) + 8 * (reg >> 2) + rbase;
            logits[(size_t)(t0 + wm * 32 + row) * NEXP + e] = acc[ntl][reg];
        }
    }
}

// ---------------------------------------------------------------------------
// K2: select — 1 wave/token, butterfly top-9 (value desc, lower index wins
// ties). Clean tokens (all 8 adjacent gaps >= DELTA) write outputs directly;
// ambiguous tokens are pushed to the refine list.
// ---------------------------------------------------------------------------
__global__ __launch_bounds__(256) void router_select(const float* __restrict__ logits,
                                                     float* __restrict__ top_vals,
                                                     float* __restrict__ top_idx,
                                                     int* __restrict__ cnt,
                                                     int* __restrict__ list) {
    const int lane = threadIdx.x & 63;
    const int t = blockIdx.x * 4 + (threadIdx.x >> 6);
    const float* lrow = logits + (size_t)t * NEXP;
    const float l0 = lrow[lane];
    const float l1 = lrow[lane + 64];
    bool r0 = false, r1 = false;
    float vals[TOPK + 1]; int idxs[TOPK + 1];
#pragma unroll
    for (int it = 0; it < TOPK + 1; ++it) {
        const float c0 = r0 ? -FLT_MAX : l0;
        const float c1 = r1 ? -FLT_MAX : l1;
        float v; int id;
        if (c1 > c0) { v = c1; id = lane + 64; }
        else         { v = c0; id = lane; }
#pragma unroll
        for (int off = 1; off < 64; off <<= 1) {
            const float ov = __shfl_xor(v, off);
            const int   oi = __shfl_xor(id, off);
            if (ov > v || (ov == v && oi < id)) { v = ov; id = oi; }
        }
        vals[it] = v; idxs[it] = id;
        if (id == lane) r0 = true;
        else if (id == lane + 64) r1 = true;
    }

    float ming = FLT_MAX;
#pragma unroll
    for (int i = 0; i < TOPK; ++i) ming = fminf(ming, vals[i] - vals[i + 1]);

    if (ming < DELTA) {
        if (lane == 0) { const int p = atomicAdd(cnt, 1); list[p] = t; }
    } else if (lane == 0) {
        const float m = vals[0];
        float ex[TOPK], s = 0.f;
#pragma unroll
        for (int i = 0; i < TOPK; ++i) { ex[i] = expf(vals[i] - m); s += ex[i]; }
        const float inv = 1.f / s;
#pragma unroll
        for (int i = 0; i < TOPK; ++i) {
            top_vals[(size_t)t * TOPK + i] = ex[i] * inv;
            top_idx[(size_t)t * TOPK + i] = (float)idxs[i];
        }
    }
}

// ---------------------------------------------------------------------------
// K3: exact fp64 refine of flagged tokens (unchanged from passing rounds).
// ---------------------------------------------------------------------------
__device__ __forceinline__ void top_cand(const float* __restrict__ lrow, int lane,
                                         float* vals, int* idxs) {
    const float l0 = lrow[lane];
    const float l1 = lrow[lane + 64];
    bool r0 = false, r1 = false;
#pragma unroll
    for (int it = 0; it < NCAND; ++it) {
        const float c0 = r0 ? -FLT_MAX : l0;
        const float c1 = r1 ? -FLT_MAX : l1;
        float v; int id;
        if (c1 > c0) { v = c1; id = lane + 64; }
        else         { v = c0; id = lane; }
#pragma unroll
        for (int off = 1; off < 64; off <<= 1) {
            const float ov = __shfl_xor(v, off);
            const int   oi = __shfl_xor(id, off);
            if (ov > v || (ov == v && oi < id)) { v = ov; id = oi; }
        }
        vals[it] = v; idxs[it] = id;
        if (id == lane) r0 = true;
        else if (id == lane + 64) r1 = true;
    }
}

__global__ __launch_bounds__(256) void router_refine(const float* __restrict__ logits,
                                                     const float* __restrict__ X,
                                                     const float* __restrict__ W,
                                                     float* __restrict__ top_vals,
                                                     float* __restrict__ top_idx,
                                                     const int* __restrict__ cnt,
                                                     const int* __restrict__ list) {
    const int lane = threadIdx.x & 63;
    const int gw = blockIdx.x * 4 + (threadIdx.x >> 6);
    const int nwaves = gridDim.x * 4;
    const int n = *cnt;

    for (int ii = gw; ii < n; ii += nwaves) {
        const int t = list[ii];
        float vals[NCAND]; int idxs[NCAND];
        top_cand(logits + (size_t)t * NEXP, lane, vals, idxs);

        const float* xr = X + (size_t)t * HIDDEN;
        double xd[32];
#pragma unroll
        for (int j = 0; j < 8; ++j) {
            const float4 v = *(const float4*)(xr + j * 256 + lane * 4);
            xd[j * 4 + 0] = (double)v.x; xd[j * 4 + 1] = (double)v.y;
            xd[j * 4 + 2] = (double)v.z; xd[j * 4 + 3] = (double)v.w;
        }
        double acc[NCAND];
#pragma unroll
        for (int c = 0; c < NCAND; ++c) {
            const float* wr = W + (size_t)idxs[c] * HIDDEN;
            double a0 = 0.0, a1 = 0.0;
#pragma unroll
            for (int j = 0; j < 8; ++j) {
                const float4 w = *(const float4*)(wr + j * 256 + lane * 4);
                a0 = fma((double)w.x, xd[j * 4 + 0], a0);
                a1 = fma((double)w.y, xd[j * 4 + 1], a1);
                a0 = fma((double)w.z, xd[j * 4 + 2], a0);
                a1 = fma((double)w.w, xd[j * 4 + 3], a1);
            }
            acc[c] = a0 + a1;
        }
#pragma unroll
        for (int c = 0; c < NCAND; ++c)
#pragma unroll
            for (int off = 1; off < 64; off <<= 1)
                acc[c] += __shfl_xor(acc[c], off);

        int rank[NCAND];
#pragma unroll
        for (int c = 0; c < NCAND; ++c) {
            int r = 0;
#pragma unroll
            for (int m = 0; m < NCAND; ++m)
                if (acc[m] > acc[c] || (acc[m] == acc[c] && idxs[m] < idxs[c])) ++r;
            rank[c] = r;
        }
        double vmax = acc[0];
#pragma unroll
        for (int c = 0; c < NCAND; ++c) if (rank[c] == 0) vmax = acc[c];
        float e[NCAND], s = 0.f;
#pragma unroll
        for (int c = 0; c < NCAND; ++c) {
            e[c] = (rank[c] < TOPK) ? expf((float)(acc[c] - vmax)) : 0.f;
            s += e[c];
        }
        const float inv = 1.f / s;
        if (lane == 0) {
#pragma unroll
            for (int c = 0; c < NCAND; ++c)
                if (rank[c] < TOPK) {
                    top_vals[(size_t)t * TOPK + rank[c]] = e[c] * inv;
                    top_idx[(size_t)t * TOPK + rank[c]] = (float)idxs[c];
                }
        }
    }
}

extern "C" void kernel_launch(void* const* d_in, const int* in_sizes, int n_in,
                              void* d_out, int out_size, void* d_ws, size_t ws_size,
                              hipStream_t stream) {
    const float* X = (const float*)d_in[0];   // [16384, 2048] f32
    const float* W = (const float*)d_in[1];   // [128, 2048] f32
    float* logits = (float*)d_out;                          // [16384,128]
    float* tvals  = logits + (size_t)TOKENS * NEXP;         // [16384,8]
    float* tidx   = tvals + (size_t)TOKENS * TOPK;          // [16384,8]

    int* cnt = (int*)d_ws;
    unsigned short* Wsplit = (unsigned short*)((char*)d_ws + 4096);      // 1 MB
    int* list = (int*)((char*)d_ws + 4096 + 2 * 1024 * 1024);            // 64 KB

    hipMemsetAsync(d_ws, 0, 64, stream);
    presplit_w<<<256, 256, 0, stream>>>(W, Wsplit);
    router_gemm<<<TOKENS / BM, 256, 0, stream>>>(X, Wsplit, logits);
    router_select<<<TOKENS / 4, 256, 0, stream>>>(logits, tvals, tidx, cnt, list);
    router_refine<<<256, 256, 0, stream>>>(logits, X, W, tvals, tidx, cnt, list);
}

// Round 7
// 293.661 us; speedup vs baseline: 1.1116x; 1.1116x over previous
//
#include <hip/hip_runtime.h>
#include <float.h>
#include <math.h>

#define TOKENS 16384
#define HIDDEN 2048
#define NEXP 128
#define TOPK 8
#define NCAND 12
#define DELTA 5e-4f

#define BM 32
#define BK 64
#define KITERS (HIDDEN / BK)   // 32

typedef float f32x16 __attribute__((ext_vector_type(16)));
typedef short bf16x8 __attribute__((ext_vector_type(8)));

__device__ __forceinline__ unsigned pack_hi(float a, float b) {
    return (__float_as_uint(a) >> 16) | (__float_as_uint(b) & 0xFFFF0000u);
}
__device__ __forceinline__ float resid(float a) {
    return a - __uint_as_float(__float_as_uint(a) & 0xFFFF0000u);
}

__device__ __forceinline__ void load_lds_16B(const void* g, void* l) {
    __builtin_amdgcn_global_load_lds(
        (const __attribute__((address_space(1))) unsigned int*)g,
        (__attribute__((address_space(3))) unsigned int*)l, 16, 0, 0);
}

// ---------------------------------------------------------------------------
// K0: pre-split W into 32x32x16-fragment-ordered bf16 hi/lo (verified r6).
// Chunk c = k16*8 + nt*2 + hl; lane l: expert = nt*32+(l&31), k = k16*16+(l>>5)*8+j.
// ---------------------------------------------------------------------------
__global__ __launch_bounds__(256) void presplit_w(const float* __restrict__ W,
                                                  unsigned short* __restrict__ Ws) {
    const int c = blockIdx.x * 256 + threadIdx.x;   // [0, 65536)
    const int lane = c & 63;
    const int q = c >> 6;
    const int hl = q & 1;
    const int nt = (q >> 1) & 3;
    const int k16 = q >> 3;
    const int e = nt * 32 + (lane & 31);
    const int k0 = k16 * 16 + (lane >> 5) * 8;
    const float* wp = W + (size_t)e * HIDDEN + k0;
    float4 a = *(const float4*)wp;
    float4 b = *(const float4*)(wp + 4);
    if (hl) {
        a.x = resid(a.x); a.y = resid(a.y); a.z = resid(a.z); a.w = resid(a.w);
        b.x = resid(b.x); b.y = resid(b.y); b.z = resid(b.z); b.w = resid(b.w);
    }
    uint4 o;
    o.x = pack_hi(a.x, a.y); o.y = pack_hi(a.z, a.w);
    o.z = pack_hi(b.x, b.y); o.w = pack_hi(b.z, b.w);
    *(uint4*)(Ws + (size_t)c * 8) = o;
}

// ---------------------------------------------------------------------------
// K1: split-bf16 GEMM, 32x32x16 MFMA. BM=32 x BN=128 x BK=64, grid 512
// (2 blocks/CU: 40KB LDS each -> latency chains of co-resident blocks
// overlap; this was the round-6 failure: grid 256 = 1 block/CU). 4 waves:
// wave w owns experts w*32..w*32+31 (nt=wid), all share the 32-token A.
// Same verified mappings as round 6 (A/B frag + C/D). Single-buffer, DMA
// issued and drained within the same iter; X prefetched 1 iter in regs.
// ---------------------------------------------------------------------------
__global__ __launch_bounds__(256) void router_gemm(const float* __restrict__ X,
                                                   const unsigned short* __restrict__ Ws,
                                                   float* __restrict__ logits) {
    __shared__ unsigned short sA[8 * 512];    // 8 KB : chunk s*2+hl
    __shared__ unsigned short sB[32 * 512];   // 32 KB: chunk s*8 + nt*2 + hl (slab order)
    const int tid = threadIdx.x;
    const int lane = tid & 63;
    const int wid = tid >> 6;
    const int t0 = blockIdx.x * BM;

    // A staging: thread -> (arow = tid>>3, aq = tid&7) loads 8 consecutive
    // floats (32 B; 8 threads cover one 256-B row). k = aq*8..aq*8+7 ->
    // chunk s = aq>>1, lane-slot = (aq&1)*32 + arow.
    const int arow = tid >> 3, aq = tid & 7;
    const int offH = ((aq >> 1) * 2 + 0) * 512 + ((aq & 1) * 32 + arow) * 8;
    const int offL = offH + 512;
    const float* Xp = X + (size_t)(t0 + arow) * HIDDEN + aq * 8;

    f32x16 acc;
#pragma unroll
    for (int r = 0; r < 16; ++r) acc[r] = 0.f;

    float4 xa = *(const float4*)(Xp);
    float4 xb = *(const float4*)(Xp + 4);

#pragma unroll 1
    for (int kt = 0; kt < KITERS; ++kt) {
        __syncthreads();   // all waves done reading LDS of prev iter
        // B DMA: this wave stages slab chunks wid*8 .. wid*8+7
        {
            const unsigned short* src = Ws + ((size_t)kt * 32 + wid * 8) * 512 + lane * 8;
            unsigned short* dst = &sB[(wid * 8) * 512];
#pragma unroll
            for (int i = 0; i < 8; ++i)
                load_lds_16B(src + i * 512, dst + i * 512);
        }
        // A stage from prefetched regs
        {
            uint4 v;
            v.x = pack_hi(xa.x, xa.y); v.y = pack_hi(xa.z, xa.w);
            v.z = pack_hi(xb.x, xb.y); v.w = pack_hi(xb.z, xb.w);
            *(uint4*)&sA[offH] = v;
            v.x = pack_hi(resid(xa.x), resid(xa.y));
            v.y = pack_hi(resid(xa.z), resid(xa.w));
            v.z = pack_hi(resid(xb.x), resid(xb.y));
            v.w = pack_hi(resid(xb.z), resid(xb.w));
            *(uint4*)&sA[offL] = v;
        }
        __syncthreads();   // drain DMA + A writes (same-iter: no cross-iter poison)

        if (kt + 1 < KITERS) {   // X prefetch lands under the MFMAs below
            const float* xp = Xp + (kt + 1) * BK;
            xa = *(const float4*)(xp);
            xb = *(const float4*)(xp + 4);
        }

        // compute: 4 k16-steps x 3 split-terms = 12 MFMA, 16 b128 reads
#pragma unroll
        for (int s = 0; s < 4; ++s) {
            const bf16x8 ah = *(const bf16x8*)&sA[(s * 2 + 0) * 512 + lane * 8];
            const bf16x8 al = *(const bf16x8*)&sA[(s * 2 + 1) * 512 + lane * 8];
            const int bb = (s * 8 + wid * 2) * 512 + lane * 8;
            const bf16x8 bh = *(const bf16x8*)&sB[bb];
            const bf16x8 bl = *(const bf16x8*)&sB[bb + 512];
            acc = __builtin_amdgcn_mfma_f32_32x32x16_bf16(ah, bh, acc, 0, 0, 0);
            acc = __builtin_amdgcn_mfma_f32_32x32x16_bf16(ah, bl, acc, 0, 0, 0);
            acc = __builtin_amdgcn_mfma_f32_32x32x16_bf16(al, bh, acc, 0, 0, 0);
        }
    }

    // C/D: col=lane&31, row=(reg&3)+8*(reg>>2)+4*(lane>>5)  (r6-verified)
    const int e = wid * 32 + (lane & 31);
    const int rbase = 4 * (lane >> 5);
#pragma unroll
    for (int reg = 0; reg < 16; ++reg) {
        const int row = (reg & 3) + 8 * (reg >> 2) + rbase;
        logits[(size_t)(t0 + row) * NEXP + e] = acc[reg];
    }
}

// ---------------------------------------------------------------------------
// K2: fused select+refine. 1 wave/token. Butterfly top-9 (value desc, lower
// index wins ties — wave-uniform result). Clean tokens (all 8 adjacent gaps
// >= DELTA; split-bf16 logit error ~1.2e-5 rms << DELTA/2) write outputs
// immediately. Flagged tokens (wave-uniform branch, no divergence) extend to
// top-12 and recompute those 12 logits exactly in fp64 (coalesced loads),
// then rank and write. No workspace, no atomics, single logits read.
// ---------------------------------------------------------------------------
__global__ __launch_bounds__(256) void router_topk(const float* __restrict__ logits,
                                                   const float* __restrict__ X,
                                                   const float* __restrict__ W,
                                                   float* __restrict__ top_vals,
                                                   float* __restrict__ top_idx) {
    const int lane = threadIdx.x & 63;
    const int t = blockIdx.x * 4 + (threadIdx.x >> 6);
    const float* lrow = logits + (size_t)t * NEXP;
    const float l0 = lrow[lane];
    const float l1 = lrow[lane + 64];
    bool r0 = false, r1 = false;
    float vals[NCAND]; int idxs[NCAND];

#pragma unroll
    for (int it = 0; it < TOPK + 1; ++it) {
        const float c0 = r0 ? -FLT_MAX : l0;
        const float c1 = r1 ? -FLT_MAX : l1;
        float v; int id;
        if (c1 > c0) { v = c1; id = lane + 64; }
        else         { v = c0; id = lane; }
#pragma unroll
        for (int off = 1; off < 64; off <<= 1) {
            const float ov = __shfl_xor(v, off);
            const int   oi = __shfl_xor(id, off);
            if (ov > v || (ov == v && oi < id)) { v = ov; id = oi; }
        }
        vals[it] = v; idxs[it] = id;
        if (id == lane) r0 = true;
        else if (id == lane + 64) r1 = true;
    }

    float ming = FLT_MAX;
#pragma unroll
    for (int i = 0; i < TOPK; ++i) ming = fminf(ming, vals[i] - vals[i + 1]);

    if (ming >= DELTA) {
        if (lane == 0) {
            const float m = vals[0];
            float ex[TOPK], s = 0.f;
#pragma unroll
            for (int i = 0; i < TOPK; ++i) { ex[i] = expf(vals[i] - m); s += ex[i]; }
            const float inv = 1.f / s;
#pragma unroll
            for (int i = 0; i < TOPK; ++i) {
                top_vals[(size_t)t * TOPK + i] = ex[i] * inv;
                top_idx[(size_t)t * TOPK + i] = (float)idxs[i];
            }
        }
        return;
    }

    // ---- slow path (wave-uniform): extend candidates to NCAND
#pragma unroll
    for (int it = TOPK + 1; it < NCAND; ++it) {
        const float c0 = r0 ? -FLT_MAX : l0;
        const float c1 = r1 ? -FLT_MAX : l1;
        float v; int id;
        if (c1 > c0) { v = c1; id = lane + 64; }
        else         { v = c0; id = lane; }
#pragma unroll
        for (int off = 1; off < 64; off <<= 1) {
            const float ov = __shfl_xor(v, off);
            const int   oi = __shfl_xor(id, off);
            if (ov > v || (ov == v && oi < id)) { v = ov; id = oi; }
        }
        vals[it] = v; idxs[it] = id;
        if (id == lane) r0 = true;
        else if (id == lane + 64) r1 = true;
    }

    // exact fp64 recompute of the NCAND candidate logits (coalesced)
    const float* xr = X + (size_t)t * HIDDEN;
    double xd[32];
#pragma unroll
    for (int j = 0; j < 8; ++j) {
        const float4 v = *(const float4*)(xr + j * 256 + lane * 4);
        xd[j * 4 + 0] = (double)v.x; xd[j * 4 + 1] = (double)v.y;
        xd[j * 4 + 2] = (double)v.z; xd[j * 4 + 3] = (double)v.w;
    }
    double acc[NCAND];
#pragma unroll
    for (int c = 0; c < NCAND; ++c) {
        const float* wr = W + (size_t)idxs[c] * HIDDEN;
        double a0 = 0.0, a1 = 0.0;
#pragma unroll
        for (int j = 0; j < 8; ++j) {
            const float4 w = *(const float4*)(wr + j * 256 + lane * 4);
            a0 = fma((double)w.x, xd[j * 4 + 0], a0);
            a1 = fma((double)w.y, xd[j * 4 + 1], a1);
            a0 = fma((double)w.z, xd[j * 4 + 2], a0);
            a1 = fma((double)w.w, xd[j * 4 + 3], a1);
        }
        acc[c] = a0 + a1;
    }
#pragma unroll
    for (int c = 0; c < NCAND; ++c)
#pragma unroll
        for (int off = 1; off < 64; off <<= 1)
            acc[c] += __shfl_xor(acc[c], off);

    int rank[NCAND];
#pragma unroll
    for (int c = 0; c < NCAND; ++c) {
        int r = 0;
#pragma unroll
        for (int m = 0; m < NCAND; ++m)
            if (acc[m] > acc[c] || (acc[m] == acc[c] && idxs[m] < idxs[c])) ++r;
        rank[c] = r;
    }
    double vmax = acc[0];
#pragma unroll
    for (int c = 0; c < NCAND; ++c) if (rank[c] == 0) vmax = acc[c];
    float ex[NCAND], s = 0.f;
#pragma unroll
    for (int c = 0; c < NCAND; ++c) {
        ex[c] = (rank[c] < TOPK) ? expf((float)(acc[c] - vmax)) : 0.f;
        s += ex[c];
    }
    const float inv = 1.f / s;
    if (lane == 0) {
#pragma unroll
        for (int c = 0; c < NCAND; ++c)
            if (rank[c] < TOPK) {
                top_vals[(size_t)t * TOPK + rank[c]] = ex[c] * inv;
                top_idx[(size_t)t * TOPK + rank[c]] = (float)idxs[c];
            }
    }
}

extern "C" void kernel_launch(void* const* d_in, const int* in_sizes, int n_in,
                              void* d_out, int out_size, void* d_ws, size_t ws_size,
                              hipStream_t stream) {
    const float* X = (const float*)d_in[0];   // [16384, 2048] f32
    const float* W = (const float*)d_in[1];   // [128, 2048] f32
    float* logits = (float*)d_out;                          // [16384,128]
    float* tvals  = logits + (size_t)TOKENS * NEXP;         // [16384,8]
    float* tidx   = tvals + (size_t)TOKENS * TOPK;          // [16384,8]

    unsigned short* Wsplit = (unsigned short*)d_ws;         // 1 MB

    presplit_w<<<256, 256, 0, stream>>>(W, Wsplit);
    router_gemm<<<TOKENS / BM, 256, 0, stream>>>(X, Wsplit, logits);
    router_topk<<<TOKENS / 4, 256, 0, stream>>>(logits, X, W, tvals, tidx);
}